// Round 12
// baseline (213.364 us; speedup 1.0000x reference)
//
#include <hip/hip_runtime.h>
#include <cstdint>
#include <cstddef>

#define E 32
#define Bsz 64
#define Lsz 2048
#define JCHUNK 128
#define NCH (Lsz / JCHUNK)   // 16
#define VSTR 152             // V^T LDS row stride in halfs (304B: ~2-way banks, 16B-aligned writes)

typedef float f32x4 __attribute__((ext_vector_type(4)));
typedef __bf16 bf16x8 __attribute__((ext_vector_type(8)));
typedef __bf16 bf16x4 __attribute__((ext_vector_type(4)));
typedef short s16x8 __attribute__((ext_vector_type(8)));
typedef short s16x4 __attribute__((ext_vector_type(4)));
typedef unsigned short u16;

typedef __attribute__((address_space(3))) unsigned int as3_u32;
typedef __attribute__((address_space(1))) const unsigned int as1_u32;

__device__ inline u16 f2bf(float f) {
    union { float f; unsigned u; } x; x.f = f;
    unsigned r = x.u + 0x7FFFu + ((x.u >> 16) & 1u);
    return (u16)(r >> 16);
}

__device__ inline float fexp2(float x) {
#if __has_builtin(__builtin_amdgcn_exp2f)
    return __builtin_amdgcn_exp2f(x);   // raw v_exp_f32
#else
    return exp2f(x);
#endif
}

// async global -> LDS, 16 B per lane; LDS dst must be wave-uniform (HW adds lane*16)
__device__ inline void glds(const void* g, void* l) {
    __builtin_amdgcn_global_load_lds((as1_u32*)g, (as3_u32*)l, 16, 0, 0);
}

// 16x16x16 mfma: D = A*B + C
__device__ inline f32x4 pv_mfma(bf16x4 a, bf16x4 b, f32x4 c) {
#if __has_builtin(__builtin_amdgcn_mfma_f32_16x16x16_bf16)
    return __builtin_amdgcn_mfma_f32_16x16x16_bf16(a, b, c, 0, 0, 0);
#elif __has_builtin(__builtin_amdgcn_mfma_f32_16x16x16bf16_1k)
    return __builtin_amdgcn_mfma_f32_16x16x16bf16_1k(
        __builtin_bit_cast(s16x4, a), __builtin_bit_cast(s16x4, b), c, 0, 0, 0);
#else
    asm volatile("s_nop 1\n\t"
                 "v_mfma_f32_16x16x16_bf16 %0, %1, %2, %0\n\t"
                 "s_nop 3"
                 : "+v"(c) : "v"(a), "v"(b));
    return c;
#endif
}

// ---------------- Full PSF mask: M[i][j] = bilinear(i,j) / sqrt(E) * log2(e), bf16 ----------------
__global__ __launch_bounds__(256) void mask_kernel(u16* __restrict__ M) {
    int g = blockIdx.x * 256 + threadIdx.x;
    int i = g >> 11, j = g & 2047;
    const float scale = 21.0f / 2048.0f;
    float si = fmaxf((i + 0.5f) * scale - 0.5f, 0.f);
    float sj = fmaxf((j + 0.5f) * scale - 0.5f, 0.f);
    int i0 = (int)si; float fi = si - (float)i0;
    int j0 = (int)sj; float fj = sj - (float)j0;
    int i0c = min(i0, 20), i1c = min(i0 + 1, 20);
    int j0c = min(j0, 20), j1c = min(j0 + 1, 20);
    int d00 = abs(i0c - j0c), d01 = abs(i0c - j1c), d10 = abs(i1c - j0c), d11 = abs(i1c - j1c);
    float t00 = __expf(-0.125f * (float)(d00 * d00));
    float t01 = __expf(-0.125f * (float)(d01 * d01));
    float t10 = __expf(-0.125f * (float)(d10 * d10));
    float t11 = __expf(-0.125f * (float)(d11 * d11));
    float m = (1.f - fi) * ((1.f - fj) * t00 + fj * t01)
            + fi * ((1.f - fj) * t10 + fj * t11);
    // * 1/sqrt(32) * log2(e) / Z, folded at compile time (Z = sum exp(-x^2/8), x=-10..10)
    m = m * (0.17677669529663687f * 1.4426950408889634f / 5.0132563952f);
    M[g] = f2bf(m);
}

// ---------------- QKV: x[B][E][L] f32 -> Q,K [B][L][E] bf16, Vt [B][E][L] bf16 ----------------
__global__ __launch_bounds__(256) void qkv_kernel(const float* __restrict__ x,
        const float* __restrict__ Wqkv, const float* __restrict__ bqkv,
        u16* __restrict__ Q, u16* __restrict__ K, u16* __restrict__ Vt) {
    int g = blockIdx.x * 256 + threadIdx.x;
    int b = g >> 11, l = g & 2047;
    float xr[E];
    #pragma unroll
    for (int c = 0; c < E; ++c) xr[c] = x[((size_t)b * E + c) * Lsz + l];

    #pragma unroll
    for (int part = 0; part < 2; ++part) {
        u16* dst = (part == 0) ? Q : K;
        s16x8 pk[4];
        #pragma unroll
        for (int e = 0; e < E; ++e) {
            int o = part * E + e;
            float acc = bqkv[o];
            #pragma unroll
            for (int c = 0; c < E; ++c) acc += xr[c] * Wqkv[o * E + c];
            pk[e >> 3][e & 7] = (short)f2bf(acc);
        }
        s16x8* dp = (s16x8*)(dst + ((size_t)b * Lsz + l) * E);
        #pragma unroll
        for (int q8 = 0; q8 < 4; ++q8) dp[q8] = pk[q8];
    }
    #pragma unroll
    for (int e = 0; e < E; ++e) {
        int o = 2 * E + e;
        float acc = bqkv[o];
        #pragma unroll
        for (int c = 0; c < E; ++c) acc += xr[c] * Wqkv[o * E + c];
        Vt[((size_t)b * E + e) * Lsz + l] = f2bf(acc);
    }
}

// ---------------- Flash attention v9: swapped PV (O^T), zero inline-asm loop ----------------
// 1024 blocks (B x L/128) x 512 threads (8 waves x 16 q-rows).
// K: glds-staged swizzled [2][128][32]h (proven v5-v8). V^T: reg-staged [2][32][VSTR]h
// (T14 issue-early/write-late). PV: O^T = mfma(A=V^T-frag, B=P-frag) -> plain ds_read_b64
// for V, no TRR, no lgkmcnt(0)/sched_barrier, epilogue divide needs NO shuffles.
__global__ __launch_bounds__(512, 4) void attn_kernel(const u16* __restrict__ Q,
        const u16* __restrict__ Kg, const u16* __restrict__ Vt,
        const u16* __restrict__ M, float* __restrict__ O) {
    extern __shared__ char smem[];
    int blk = blockIdx.x;
    int b = blk >> 4;
    int qblk = blk & 15;
    int tid = threadIdx.x;
    int wave = tid >> 6, lane = tid & 63;
    int lrow = lane & 15, kgrp = lane >> 4;
    int qbase = qblk * 128 + wave * 16;

    const size_t bLE = (size_t)b * Lsz * E;
    bf16x8 qf = *(const bf16x8*)(Q + bLE + (size_t)(qbase + lrow) * E + kgrp * 8);
    const u16* mp0 = M + (size_t)(qbase + lrow) * Lsz + kgrp * 4;

    // K staging (v8-verified): LDS[row][slot] = K[row][slot ^ (row&3)] (16B slots)
    const char* kcbase = (const char*)(Kg + bLE);
    int row = tid >> 2, s4 = tid & 3;
    int ksrc = row * 64 + ((s4 ^ (row & 3)) << 4);
    u16* smem_h = (u16*)smem;
    int kslot = (kgrp ^ (lrow & 3)) * 8;          // swizzled read slot (halfs)

    // V^T staging: thread (ev, sv) moves Vt[b][ev][jco + sv*8 .. +7] (16B)
    const u16* vtb = Vt + bLE;
    int ev = tid >> 4, sv = tid & 15;
    u16* vls = smem_h + 8192;                     // V^T region: [2][32][VSTR] halfs

#define STAGE_K(bufn, jc_) \
    glds(kcbase + (size_t)(jc_) * 8192 + ksrc, smem + (bufn) * 8192 + wave * 1024)
#define VLOAD(jc_) (*(const s16x8*)(vtb + (size_t)ev * Lsz + (jc_) * JCHUNK + sv * 8))
#define VWRITE(bufn, vr_) (*(s16x8*)(vls + (bufn) * (32 * VSTR) + ev * VSTR + sv * 8) = (vr_))

    f32x4 o0 = {0,0,0,0}, o1 = {0,0,0,0};
    float dsum = 0.f;

    // one 16-j tile: QK mfma -> exp -> P as B-frag; V^T rows as A-frag -> O^T accum
#define JT(jt, mm) do { \
    bf16x8 kf = *(const bf16x8*)(smem_h + buf * 4096 + ((jt) * 16 + lrow) * 32 + kslot); \
    f32x4 zc = {0,0,0,0}; \
    f32x4 s0 = __builtin_amdgcn_mfma_f32_16x16x32_bf16(kf, qf, zc, 0, 0, 0); \
    bf16x4 pa; \
    _Pragma("unroll") for (int r = 0; r < 4; ++r) { \
        float p = fexp2(s0[r] * (float)(mm)[r]); \
        dsum += p; pa[r] = (__bf16)p; \
    } \
    const u16* vrd = vls + buf * (32 * VSTR) + (jt) * 16 + kgrp * 4; \
    bf16x4 vf0 = *(const bf16x4*)(vrd + lrow * VSTR); \
    bf16x4 vf1 = *(const bf16x4*)(vrd + (16 + lrow) * VSTR); \
    o0 = pv_mfma(vf0, pa, o0); \
    o1 = pv_mfma(vf1, pa, o1); \
} while (0)

    int buf = 0;
    {   // prologue: stage chunk 0
        STAGE_K(0, 0);
        s16x8 vr = VLOAD(0);
        VWRITE(0, vr);
        __syncthreads();
    }
    #pragma unroll 1
    for (int jc = 0; jc < NCH; ++jc) {
        s16x8 vr = {};
        if (jc + 1 < NCH) {
            STAGE_K(buf ^ 1, jc + 1);          // issue K early (glds)
            vr = VLOAD(jc + 1);                // issue V early (to regs)
        }
        const int jco = jc * JCHUNK;
        // mask for the whole chunk, hoisted as named regs (8 x 8B loads)
        bf16x4 m0 = *(const bf16x4*)(mp0 + jco);
        bf16x4 m1 = *(const bf16x4*)(mp0 + jco + 16);
        bf16x4 m2 = *(const bf16x4*)(mp0 + jco + 32);
        bf16x4 m3 = *(const bf16x4*)(mp0 + jco + 48);
        bf16x4 m4 = *(const bf16x4*)(mp0 + jco + 64);
        bf16x4 m5 = *(const bf16x4*)(mp0 + jco + 80);
        bf16x4 m6 = *(const bf16x4*)(mp0 + jco + 96);
        bf16x4 m7 = *(const bf16x4*)(mp0 + jco + 112);
        JT(0, m0); JT(1, m1); JT(2, m2); JT(3, m3);
        JT(4, m4); JT(5, m5); JT(6, m6); JT(7, m7);
        if (jc + 1 < NCH) VWRITE(buf ^ 1, vr); // write-late (T14)
        __syncthreads();                       // drains stage; LDS reuse safe
        buf ^= 1;
    }
#undef JT
#undef STAGE_K
#undef VLOAD
#undef VWRITE

    // denominator: dsum is per (q=lrow, kgrp j-slots); reduce across kgrp groups
    dsum += __shfl_xor(dsum, 16);
    dsum += __shfl_xor(dsum, 32);
    float inv = 1.0f / dsum;                   // lane's q-row = lrow: matches O^T layout!
    // O^T output: lane holds O[q=lrow][e=kgrp*4+r] (o0) and e=16+kgrp*4+r (o1)
    float* orow = O + ((size_t)b * Lsz + qbase + lrow) * E + kgrp * 4;
    f32x4 r0 = {o0[0]*inv, o0[1]*inv, o0[2]*inv, o0[3]*inv};
    f32x4 r1 = {o1[0]*inv, o1[1]*inv, o1[2]*inv, o1[3]*inv};
    *(f32x4*)(orow)      = r0;
    *(f32x4*)(orow + 16) = r1;
}

// ---------------- Output projection: O[B][L][E] f32 -> y[B][E][L] f32 ----------------
__global__ __launch_bounds__(256) void oproj_kernel(const float* __restrict__ O,
        const float* __restrict__ Wout, const float* __restrict__ bout,
        float* __restrict__ y) {
    int g = blockIdx.x * 256 + threadIdx.x;
    int b = g >> 11, l = g & 2047;
    float orow[E];
    const float* src = O + ((size_t)b * Lsz + l) * E;
    #pragma unroll
    for (int e = 0; e < E; e += 4) {
        f32x4 t = *(const f32x4*)(src + e);
        orow[e] = t[0]; orow[e + 1] = t[1]; orow[e + 2] = t[2]; orow[e + 3] = t[3];
    }
    #pragma unroll
    for (int c = 0; c < E; ++c) {
        float acc = bout[c];
        #pragma unroll
        for (int e = 0; e < E; ++e) acc += orow[e] * Wout[c * E + e];
        y[((size_t)b * E + c) * Lsz + l] = acc;
    }
}

extern "C" void kernel_launch(void* const* d_in, const int* in_sizes, int n_in,
                              void* d_out, int out_size, void* d_ws, size_t ws_size,
                              hipStream_t stream) {
    const float* x    = (const float*)d_in[0];
    const float* Wqkv = (const float*)d_in[1];
    const float* bqkv = (const float*)d_in[2];
    const float* Wout = (const float*)d_in[3];
    const float* bout = (const float*)d_in[4];
    float* y = (float*)d_out;

    char* ws = (char*)d_ws;
    const size_t szQ = (size_t)Bsz * Lsz * E * sizeof(u16);   // 8.39 MB
    const size_t szM = (size_t)Lsz * Lsz * sizeof(u16);       // 8.39 MB
    u16* Q   = (u16*)(ws);
    u16* K   = (u16*)(ws + szQ);
    u16* Vt  = (u16*)(ws + 2 * szQ);
    u16* M   = (u16*)(ws + 3 * szQ);
    float* O = (float*)(ws + 3 * szQ + szM);                  // 16.78 MB f32

    const int lds_bytes = 16384 + 2 * (32 * VSTR) * 2;        // K dbuf + V^T dbuf = 35840

    hipLaunchKernelGGL(mask_kernel, dim3((Lsz * Lsz) / 256), dim3(256), 0, stream, M);
    hipLaunchKernelGGL(qkv_kernel, dim3((Bsz * Lsz) / 256), dim3(256), 0, stream,
                       x, Wqkv, bqkv, Q, K, Vt);
    hipLaunchKernelGGL(attn_kernel, dim3(Bsz * (Lsz / 128)), dim3(512), lds_bytes, stream,
                       Q, K, Vt, M, O);
    hipLaunchKernelGGL(oproj_kernel, dim3((Bsz * Lsz) / 256), dim3(256), 0, stream,
                       O, Wout, bout, y);
}

// Round 13
// 199.918 us; speedup vs baseline: 1.0673x; 1.0673x over previous
//
#include <hip/hip_runtime.h>
#include <cstdint>
#include <cstddef>

#define E 32
#define Bsz 64
#define Lsz 2048
#define JCHUNK 128
#define NCH (Lsz / JCHUNK)   // 16
#define VSTR 136             // V^T LDS row stride in halfs: word-stride 68 == 4 (mod 8) -> 2-way banks (free)

typedef float f32x4 __attribute__((ext_vector_type(4)));
typedef __bf16 bf16x8 __attribute__((ext_vector_type(8)));
typedef __bf16 bf16x4 __attribute__((ext_vector_type(4)));
typedef short s16x8 __attribute__((ext_vector_type(8)));
typedef short s16x4 __attribute__((ext_vector_type(4)));
typedef unsigned short u16;

typedef __attribute__((address_space(3))) unsigned int as3_u32;
typedef __attribute__((address_space(1))) const unsigned int as1_u32;

__device__ inline u16 f2bf(float f) {
    union { float f; unsigned u; } x; x.f = f;
    unsigned r = x.u + 0x7FFFu + ((x.u >> 16) & 1u);
    return (u16)(r >> 16);
}

__device__ inline float fexp2(float x) {
#if __has_builtin(__builtin_amdgcn_exp2f)
    return __builtin_amdgcn_exp2f(x);   // raw v_exp_f32
#else
    return exp2f(x);
#endif
}

// async global -> LDS, 16 B per lane; LDS dst must be wave-uniform (HW adds lane*16)
__device__ inline void glds(const void* g, void* l) {
    __builtin_amdgcn_global_load_lds((as1_u32*)g, (as3_u32*)l, 16, 0, 0);
}

// 16x16x16 mfma: D = A*B + C
__device__ inline f32x4 pv_mfma(bf16x4 a, bf16x4 b, f32x4 c) {
#if __has_builtin(__builtin_amdgcn_mfma_f32_16x16x16_bf16)
    return __builtin_amdgcn_mfma_f32_16x16x16_bf16(a, b, c, 0, 0, 0);
#elif __has_builtin(__builtin_amdgcn_mfma_f32_16x16x16bf16_1k)
    return __builtin_amdgcn_mfma_f32_16x16x16bf16_1k(
        __builtin_bit_cast(s16x4, a), __builtin_bit_cast(s16x4, b), c, 0, 0, 0);
#else
    asm volatile("s_nop 1\n\t"
                 "v_mfma_f32_16x16x16_bf16 %0, %1, %2, %0\n\t"
                 "s_nop 3"
                 : "+v"(c) : "v"(a), "v"(b));
    return c;
#endif
}

// ---------------- Full PSF mask: M[i][j] = bilinear(i,j) / sqrt(E) * log2(e), bf16 ----------------
__global__ __launch_bounds__(256) void mask_kernel(u16* __restrict__ M) {
    int g = blockIdx.x * 256 + threadIdx.x;
    int i = g >> 11, j = g & 2047;
    const float scale = 21.0f / 2048.0f;
    float si = fmaxf((i + 0.5f) * scale - 0.5f, 0.f);
    float sj = fmaxf((j + 0.5f) * scale - 0.5f, 0.f);
    int i0 = (int)si; float fi = si - (float)i0;
    int j0 = (int)sj; float fj = sj - (float)j0;
    int i0c = min(i0, 20), i1c = min(i0 + 1, 20);
    int j0c = min(j0, 20), j1c = min(j0 + 1, 20);
    int d00 = abs(i0c - j0c), d01 = abs(i0c - j1c), d10 = abs(i1c - j0c), d11 = abs(i1c - j1c);
    float t00 = __expf(-0.125f * (float)(d00 * d00));
    float t01 = __expf(-0.125f * (float)(d01 * d01));
    float t10 = __expf(-0.125f * (float)(d10 * d10));
    float t11 = __expf(-0.125f * (float)(d11 * d11));
    float m = (1.f - fi) * ((1.f - fj) * t00 + fj * t01)
            + fi * ((1.f - fj) * t10 + fj * t11);
    // * 1/sqrt(32) * log2(e) / Z, folded at compile time (Z = sum exp(-x^2/8), x=-10..10)
    m = m * (0.17677669529663687f * 1.4426950408889634f / 5.0132563952f);
    M[g] = f2bf(m);
}

// ---------------- QKV: x[B][E][L] f32 -> Q,K [B][L][E] bf16, Vt [B][E][L] bf16 ----------------
__global__ __launch_bounds__(256) void qkv_kernel(const float* __restrict__ x,
        const float* __restrict__ Wqkv, const float* __restrict__ bqkv,
        u16* __restrict__ Q, u16* __restrict__ K, u16* __restrict__ Vt) {
    int g = blockIdx.x * 256 + threadIdx.x;
    int b = g >> 11, l = g & 2047;
    float xr[E];
    #pragma unroll
    for (int c = 0; c < E; ++c) xr[c] = x[((size_t)b * E + c) * Lsz + l];

    #pragma unroll
    for (int part = 0; part < 2; ++part) {
        u16* dst = (part == 0) ? Q : K;
        s16x8 pk[4];
        #pragma unroll
        for (int e = 0; e < E; ++e) {
            int o = part * E + e;
            float acc = bqkv[o];
            #pragma unroll
            for (int c = 0; c < E; ++c) acc += xr[c] * Wqkv[o * E + c];
            pk[e >> 3][e & 7] = (short)f2bf(acc);
        }
        s16x8* dp = (s16x8*)(dst + ((size_t)b * Lsz + l) * E);
        #pragma unroll
        for (int q8 = 0; q8 < 4; ++q8) dp[q8] = pk[q8];
    }
    #pragma unroll
    for (int e = 0; e < E; ++e) {
        int o = 2 * E + e;
        float acc = bqkv[o];
        #pragma unroll
        for (int c = 0; c < E; ++c) acc += xr[c] * Wqkv[o * E + c];
        Vt[((size_t)b * E + e) * Lsz + l] = f2bf(acc);
    }
}

// ---------------- Flash attention v10: phase-split chunks (A: QK, B: softmax, C: PV) ----------------
// 1024 blocks (B x L/128) x 512 threads (8 waves x 16 q-rows).
// K: glds-staged swizzled [2][128][32]h. V^T: reg-staged [2][32][VSTR]h (T14).
// Each phase is a long run of independent same-pipe ops -> compiler can pipeline
// all 8 ds_read->MFMA chains instead of serializing one JT at a time.
__global__ __launch_bounds__(512, 4) void attn_kernel(const u16* __restrict__ Q,
        const u16* __restrict__ Kg, const u16* __restrict__ Vt,
        const u16* __restrict__ M, float* __restrict__ O) {
    extern __shared__ char smem[];
    int blk = blockIdx.x;
    int b = blk >> 4;
    int qblk = blk & 15;
    int tid = threadIdx.x;
    int wave = tid >> 6, lane = tid & 63;
    int lrow = lane & 15, kgrp = lane >> 4;
    int qbase = qblk * 128 + wave * 16;

    const size_t bLE = (size_t)b * Lsz * E;
    bf16x8 qf = *(const bf16x8*)(Q + bLE + (size_t)(qbase + lrow) * E + kgrp * 8);
    const u16* mp0 = M + (size_t)(qbase + lrow) * Lsz + kgrp * 4;

    // K staging (v5-v9 verified): LDS[row][slot] = K[row][slot ^ (row&3)] (16B slots)
    const char* kcbase = (const char*)(Kg + bLE);
    int row = tid >> 2, s4 = tid & 3;
    int ksrc = row * 64 + ((s4 ^ (row & 3)) << 4);
    u16* smem_h = (u16*)smem;
    int kslot = (kgrp ^ (lrow & 3)) * 8;          // swizzled read slot (halfs)

    // V^T staging: thread (ev, sv) moves Vt[b][ev][jco + sv*8 .. +7] (16B)
    const u16* vtb = Vt + bLE;
    int ev = tid >> 4, sv = tid & 15;
    u16* vls = smem_h + 8192;                     // V^T region: [2][32][VSTR] halfs

#define STAGE_K(bufn, jc_) \
    glds(kcbase + (size_t)(jc_) * 8192 + ksrc, smem + (bufn) * 8192 + wave * 1024)
#define VLOAD(jc_) (*(const s16x8*)(vtb + (size_t)ev * Lsz + (jc_) * JCHUNK + sv * 8))
#define VWRITE(bufn, vr_) (*(s16x8*)(vls + (bufn) * (32 * VSTR) + ev * VSTR + sv * 8) = (vr_))

    f32x4 o0 = {0,0,0,0}, o1 = {0,0,0,0};
    float dsum = 0.f;

    int buf = 0;
    {   // prologue: stage chunk 0
        STAGE_K(0, 0);
        s16x8 vr = VLOAD(0);
        VWRITE(0, vr);
        __syncthreads();
    }
    #pragma unroll 1
    for (int jc = 0; jc < NCH; ++jc) {
        s16x8 vr = {};
        if (jc + 1 < NCH) {
            STAGE_K(buf ^ 1, jc + 1);          // issue K early (glds)
            vr = VLOAD(jc + 1);                // issue V early (to regs)
        }
        const int jco = jc * JCHUNK;
        // mask for the whole chunk (8 x 8B loads, hoisted)
        bf16x4 mm[8];
        #pragma unroll
        for (int jt = 0; jt < 8; ++jt)
            mm[jt] = *(const bf16x4*)(mp0 + jco + jt * 16);

        __builtin_amdgcn_s_setprio(1);
        // ---- Phase A: 8 independent {K ds_read -> QK MFMA} ----
        f32x4 s[8];
        #pragma unroll
        for (int jt = 0; jt < 8; ++jt) {
            bf16x8 kf = *(const bf16x8*)(smem_h + buf * 4096 + (jt * 16 + lrow) * 32 + kslot);
            f32x4 zc = {0,0,0,0};
            s[jt] = __builtin_amdgcn_mfma_f32_16x16x32_bf16(kf, qf, zc, 0, 0, 0);
        }
        __builtin_amdgcn_s_setprio(0);
        // ---- Phase B: pure-VALU softmax burst (32 exp) ----
        bf16x4 pa[8];
        #pragma unroll
        for (int jt = 0; jt < 8; ++jt) {
            #pragma unroll
            for (int r = 0; r < 4; ++r) {
                float p = fexp2(s[jt][r] * (float)mm[jt][r]);
                dsum += p;
                pa[jt][r] = (__bf16)p;
            }
        }
        __builtin_amdgcn_s_setprio(1);
        // ---- Phase C: 16 independent {V ds_read_b64 -> PV MFMA} ----
        #pragma unroll
        for (int jt = 0; jt < 8; ++jt) {
            const u16* vrd = vls + buf * (32 * VSTR) + jt * 16 + kgrp * 4;
            bf16x4 vf0 = *(const bf16x4*)(vrd + lrow * VSTR);
            bf16x4 vf1 = *(const bf16x4*)(vrd + (16 + lrow) * VSTR);
            o0 = pv_mfma(vf0, pa[jt], o0);
            o1 = pv_mfma(vf1, pa[jt], o1);
        }
        __builtin_amdgcn_s_setprio(0);
        if (jc + 1 < NCH) VWRITE(buf ^ 1, vr); // write-late (T14)
        __syncthreads();                       // drains stage; LDS reuse safe
        buf ^= 1;
    }
#undef STAGE_K
#undef VLOAD
#undef VWRITE

    // denominator: dsum is per (q=lrow, this kgrp's j-slots); reduce across kgrp groups
    dsum += __shfl_xor(dsum, 16);
    dsum += __shfl_xor(dsum, 32);
    float inv = 1.0f / dsum;                   // lane's q-row = lrow: matches O^T layout
    // O^T output: lane holds O[q=lrow][e=kgrp*4+r] (o0) and e=16+kgrp*4+r (o1)
    float* orow = O + ((size_t)b * Lsz + qbase + lrow) * E + kgrp * 4;
    f32x4 r0 = {o0[0]*inv, o0[1]*inv, o0[2]*inv, o0[3]*inv};
    f32x4 r1 = {o1[0]*inv, o1[1]*inv, o1[2]*inv, o1[3]*inv};
    *(f32x4*)(orow)      = r0;
    *(f32x4*)(orow + 16) = r1;
}

// ---------------- Output projection: O[B][L][E] f32 -> y[B][E][L] f32 ----------------
__global__ __launch_bounds__(256) void oproj_kernel(const float* __restrict__ O,
        const float* __restrict__ Wout, const float* __restrict__ bout,
        float* __restrict__ y) {
    int g = blockIdx.x * 256 + threadIdx.x;
    int b = g >> 11, l = g & 2047;
    float orow[E];
    const float* src = O + ((size_t)b * Lsz + l) * E;
    #pragma unroll
    for (int e = 0; e < E; e += 4) {
        f32x4 t = *(const f32x4*)(src + e);
        orow[e] = t[0]; orow[e + 1] = t[1]; orow[e + 2] = t[2]; orow[e + 3] = t[3];
    }
    #pragma unroll
    for (int c = 0; c < E; ++c) {
        float acc = bout[c];
        #pragma unroll
        for (int e = 0; e < E; ++e) acc += orow[e] * Wout[c * E + e];
        y[((size_t)b * E + c) * Lsz + l] = acc;
    }
}

extern "C" void kernel_launch(void* const* d_in, const int* in_sizes, int n_in,
                              void* d_out, int out_size, void* d_ws, size_t ws_size,
                              hipStream_t stream) {
    const float* x    = (const float*)d_in[0];
    const float* Wqkv = (const float*)d_in[1];
    const float* bqkv = (const float*)d_in[2];
    const float* Wout = (const float*)d_in[3];
    const float* bout = (const float*)d_in[4];
    float* y = (float*)d_out;

    char* ws = (char*)d_ws;
    const size_t szQ = (size_t)Bsz * Lsz * E * sizeof(u16);   // 8.39 MB
    const size_t szM = (size_t)Lsz * Lsz * sizeof(u16);       // 8.39 MB
    u16* Q   = (u16*)(ws);
    u16* K   = (u16*)(ws + szQ);
    u16* Vt  = (u16*)(ws + 2 * szQ);
    u16* M   = (u16*)(ws + 3 * szQ);
    float* O = (float*)(ws + 3 * szQ + szM);                  // 16.78 MB f32

    const int lds_bytes = 16384 + 2 * (32 * VSTR) * 2;        // K dbuf + V^T dbuf = 33792

    hipLaunchKernelGGL(mask_kernel, dim3((Lsz * Lsz) / 256), dim3(256), 0, stream, M);
    hipLaunchKernelGGL(qkv_kernel, dim3((Bsz * Lsz) / 256), dim3(256), 0, stream,
                       x, Wqkv, bqkv, Q, K, Vt);
    hipLaunchKernelGGL(attn_kernel, dim3(Bsz * (Lsz / 128)), dim3(512), lds_bytes, stream,
                       Q, K, Vt, M, O);
    hipLaunchKernelGGL(oproj_kernel, dim3((Bsz * Lsz) / 256), dim3(256), 0, stream,
                       O, Wout, bout, y);
}